// Round 3
// baseline (3317.318 us; speedup 1.0000x reference)
//
#include <hip/hip_runtime.h>

typedef unsigned short ushort_t;
typedef unsigned int u32;
typedef __attribute__((ext_vector_type(8))) short bf16x8;
typedef __attribute__((ext_vector_type(4))) float f32x4;
typedef __attribute__((ext_vector_type(2))) float f32x2;
typedef __attribute__((ext_vector_type(4))) u32 u32x4;

#define NTOT 262144  // B*D columns

__device__ __forceinline__ float b2f(ushort_t u) {
    return __builtin_bit_cast(float, (u32)u << 16);
}
__device__ __forceinline__ ushort_t f2b_rne(float f) {
    u32 u = __builtin_bit_cast(u32, f);
    u32 r = u + 0x7FFFu + ((u >> 16) & 1u);
    return (ushort_t)(r >> 16);
}
// (x0_even, x0_odd) * xif -> packed bf16 dword (RNE), 2 VALU ops
__device__ __forceinline__ u32 scale_pack(f32x2 xp, f32x2 s) {
    f32x2 d;
    asm("v_pk_mul_f32 %0, %1, %2" : "=v"(d) : "v"(xp), "v"(s));
    u32 r;
    asm("v_cvt_pk_bf16_f32 %0, %1, %2" : "=v"(r) : "v"(d[0]), "v"(d[1]));
    return r;
}
__device__ __forceinline__ void gl_lds16(const ushort_t* g, ushort_t* l) {
    __builtin_amdgcn_global_load_lds(
        (const __attribute__((address_space(1))) u32*)g,
        (__attribute__((address_space(3))) u32*)l, 16, 0, 0);
}

// ---- prep: x (B,64,32) f32 -> x0bf bf16 [n=(b*32+d)][64 h] (RNE) ----
__global__ void cin_prep_x0bf(const float* __restrict__ x, ushort_t* __restrict__ x0bf) {
    __shared__ float xs[64 * 33];
    const int b = blockIdx.x, t = threadIdx.x;
    const float4* src = (const float4*)(x + (size_t)b * 2048);
#pragma unroll
    for (int i = 0; i < 2; ++i) {
        float4 f = src[t + 256 * i];
        int e = (t + 256 * i) * 4;
        int h = e >> 5, d = e & 31;
        xs[h * 33 + d]     = f.x;
        xs[h * 33 + d + 1] = f.y;
        xs[h * 33 + d + 2] = f.z;
        xs[h * 33 + d + 3] = f.w;
    }
    __syncthreads();
    const int d = t >> 3, j8 = t & 7;
    u32 w[4];
#pragma unroll
    for (int q = 0; q < 4; ++q) {
        int h0 = j8 * 8 + 2 * q;
        w[q] = (u32)f2b_rne(xs[h0 * 33 + d]) | ((u32)f2b_rne(xs[(h0 + 1) * 33 + d]) << 16);
    }
    uint4 o; o.x = w[0]; o.y = w[1]; o.z = w[2]; o.w = w[3];
    *(uint4*)(x0bf + ((size_t)b * 32 + d) * 64 + j8 * 8) = o;
}

// ---- prep: x (B,64,32) f32 -> x0T bf16 [h=64][n=262144] (RNE) ----
__global__ void cin_prep_x0T(const float* __restrict__ x, ushort_t* __restrict__ x0T) {
    const int b = blockIdx.x, t = threadIdx.x;
    const int h = t >> 2, c = t & 3;
    const float* s = x + (size_t)b * 2048 + h * 32 + c * 8;
    u32 w[4];
#pragma unroll
    for (int q = 0; q < 4; ++q)
        w[q] = (u32)f2b_rne(s[2 * q]) | ((u32)f2b_rne(s[2 * q + 1]) << 16);
    uint4 o; o.x = w[0]; o.y = w[1]; o.z = w[2]; o.w = w[3];
    *(uint4*)(x0T + (size_t)h * NTOT + (size_t)b * 32 + c * 8) = o;
}

// ---- prep: K (128,G,64) f32 -> Kp bf16 [g][k][64] with XOR swizzle baked in ----
__global__ void cin_prep_k2(const float* __restrict__ K, ushort_t* __restrict__ Kp, int G) {
    const int g = blockIdx.x, t = threadIdx.x;
    const int k = t >> 1, j0 = (t & 1) * 16;
    const float* s = K + ((size_t)k * G + g) * 64 + j0 * 2;
    u32* dst = (u32*)(Kp + (size_t)g * 8192 + k * 64);
    const int swc = k & 7;
#pragma unroll
    for (int c = 0; c < 4; ++c) {
        u32 w[4];
#pragma unroll
        for (int q = 0; q < 4; ++q) {
            int e = (c * 4 + q) * 2;
            w[q] = (u32)f2b_rne(s[e]) | ((u32)f2b_rne(s[e + 1]) << 16);
        }
        uint4 o; o.x = w[0]; o.y = w[1]; o.z = w[2]; o.w = w[3];
        *(uint4*)(dst + (((j0 >> 2) + c) ^ swc) * 4) = o;
    }
}

// ---- layer: fm[k,n] = relu( sum_g sum_h K[k,g,h]*xi[g,n]*x0[n,h] + bias[k] )
// xi layout [g][n]; fm stored [k][n]; K double-buffered LDS; xi triple-buffered 256B LDS.
template <int G, bool STORE_FM>
__launch_bounds__(256, 3)
__global__ void cin_layer3(const ushort_t* __restrict__ x0bf,   // [NTOT][64]
                           const ushort_t* __restrict__ xi_src, // [G][NTOT]
                           const ushort_t* __restrict__ Kp,     // [G][128][64] swizzled
                           const float* __restrict__ bias,      // [128]
                           ushort_t* __restrict__ fm_out,       // [128][NTOT]
                           float* __restrict__ out,             // [B][384]
                           int layer_off) {
    __shared__ ushort_t k_lds[2][8192];   // 2 x 16 KB
    __shared__ ushort_t xi_lds[3 * 128];  // 3 x 256 B

    const int t = threadIdx.x;
    const int wg = blockIdx.x;
    const int lane = t & 63;
    const int wave = t >> 6;
    const int wm = wave >> 1, wn = wave & 1;
    const int col = lane & 15, g4 = lane >> 4;
    const int swz = (col & 7) << 3;
    const size_t n0 = (size_t)wg * 128;

    // ---- prologue: issue K(0), xi(0), xi(1); load x0 base regs ----
    {
        const ushort_t* src = Kp + (size_t)t * 8;
        ushort_t* dst = k_lds[0] + t * 8;
#pragma unroll
        for (int i = 0; i < 4; ++i) gl_lds16(src + i * 2048, dst + i * 2048);
        if (t < 16) {
            gl_lds16(xi_src + n0 + t * 8, xi_lds + t * 8);
            gl_lds16(xi_src + NTOT + n0 + t * 8, xi_lds + 128 + t * 8);
        }
    }
    f32x2 xb2[4][8];  // x0 base as (even,odd) f32 pairs: [nf][ks2*4+q]
#pragma unroll
    for (int nf = 0; nf < 4; ++nf) {
        const size_t n_g = n0 + wn * 64 + nf * 16 + col;
#pragma unroll
        for (int ks2 = 0; ks2 < 2; ++ks2) {
            u32x4 v = *(const u32x4*)(x0bf + n_g * 64 + ks2 * 32 + g4 * 8);
#pragma unroll
            for (int q = 0; q < 4; ++q) {
                f32x2 p;
                p[0] = __builtin_bit_cast(float, v[q] << 16);
                p[1] = __builtin_bit_cast(float, v[q] & 0xFFFF0000u);
                xb2[nf][ks2 * 4 + q] = p;
            }
        }
    }

    f32x4 acc[4][4];
#pragma unroll
    for (int a = 0; a < 4; ++a)
#pragma unroll
        for (int b = 0; b < 4; ++b) acc[a][b] = (f32x4){0.f, 0.f, 0.f, 0.f};

    __syncthreads();  // drains all gload_lds

    float xifA[4], xifB[4];
#pragma unroll
    for (int nf = 0; nf < 4; ++nf)
        xifA[nf] = b2f(xi_lds[wn * 64 + nf * 16 + col]);

    int bi_nxt = 1, bi_iss = 2;

    auto ITER = [&](int gg, float (&cur)[4], float (&nxt)[4]) {
        // issue next K tile + xi row (g+2)
        if (gg + 1 < G) {
            const ushort_t* src = Kp + (size_t)(gg + 1) * 8192 + (size_t)t * 8;
            ushort_t* dst = k_lds[(gg + 1) & 1] + t * 8;
#pragma unroll
            for (int i = 0; i < 4; ++i) gl_lds16(src + i * 2048, dst + i * 2048);
        }
        if (gg + 2 < G && t < 16)
            gl_lds16(xi_src + (size_t)(gg + 2) * NTOT + n0 + t * 8,
                     xi_lds + bi_iss * 128 + t * 8);
        // B fragments in-register: pk_mul + cvt_pk per dword
        bf16x8 bw[4][2];
#pragma unroll
        for (int nf = 0; nf < 4; ++nf) {
            f32x2 s; s[0] = cur[nf]; s[1] = cur[nf];
#pragma unroll
            for (int ks2 = 0; ks2 < 2; ++ks2) {
                u32x4 wv;
#pragma unroll
                for (int q = 0; q < 4; ++q)
                    wv[q] = scale_pack(xb2[nf][ks2 * 4 + q], s);
                bw[nf][ks2] = __builtin_bit_cast(bf16x8, wv);
            }
        }
        // A fragments + 32 MFMA
        const ushort_t* kbuf = k_lds[gg & 1];
#pragma unroll
        for (int ks2 = 0; ks2 < 2; ++ks2) {
            bf16x8 af[4];
#pragma unroll
            for (int mf = 0; mf < 4; ++mf) {
                const int row = wm * 64 + mf * 16 + col;
                af[mf] = *(const bf16x8*)(kbuf + row * 64 + ((ks2 * 32 + g4 * 8) ^ swz));
            }
            __builtin_amdgcn_s_setprio(1);
#pragma unroll
            for (int mf = 0; mf < 4; ++mf)
#pragma unroll
                for (int nf = 0; nf < 4; ++nf)
                    acc[mf][nf] = __builtin_amdgcn_mfma_f32_16x16x32_bf16(
                        af[mf], bw[nf][ks2], acc[mf][nf], 0, 0, 0);
            __builtin_amdgcn_s_setprio(0);
        }
        // register-prefetch xi(g+1) from its already-landed LDS buffer
        if (gg + 1 < G) {
#pragma unroll
            for (int nf = 0; nf < 4; ++nf)
                nxt[nf] = b2f(xi_lds[bi_nxt * 128 + wn * 64 + nf * 16 + col]);
        }
        __syncthreads();  // K(g+1)/xi(g+2) landed; k_lds[gg&1] free
        bi_nxt = bi_iss;
        bi_iss = (bi_iss == 2) ? 0 : bi_iss + 1;
    };

    for (int g = 0; g < G; g += 2) {
        ITER(g, xifA, xifB);
        ITER(g + 1, xifB, xifA);
    }

    // ---- epilogue: bias+relu, fm [k][n] store, pooled d-sum -> out ----
#pragma unroll
    for (int mf = 0; mf < 4; ++mf) {
        const int kk = wm * 64 + mf * 16 + g4 * 4;
        const float4 bs = *(const float4*)(bias + kk);
        float pool[2][4] = {{0.f, 0.f, 0.f, 0.f}, {0.f, 0.f, 0.f, 0.f}};
#pragma unroll
        for (int nf = 0; nf < 4; ++nf) {
            const size_t n_g = n0 + wn * 64 + nf * 16 + col;
#pragma unroll
            for (int r = 0; r < 4; ++r) {
                float vv = acc[mf][nf][r] + ((r == 0) ? bs.x : (r == 1) ? bs.y : (r == 2) ? bs.z : bs.w);
                vv = fmaxf(vv, 0.f);
                if (STORE_FM) fm_out[(size_t)(kk + r) * NTOT + n_g] = f2b_rne(vv);
                pool[nf >> 1][r] += vv;
            }
        }
#pragma unroll
        for (int bi = 0; bi < 2; ++bi) {
#pragma unroll
            for (int r = 0; r < 4; ++r) {
                float s = pool[bi][r];
                s += __shfl_xor(s, 1, 16);
                s += __shfl_xor(s, 2, 16);
                s += __shfl_xor(s, 4, 16);
                s += __shfl_xor(s, 8, 16);
                pool[bi][r] = s;
            }
            if (col == 0) {
                const long b = (long)wg * 4 + wn * 2 + bi;
                float4 o;
                o.x = pool[bi][0]; o.y = pool[bi][1]; o.z = pool[bi][2]; o.w = pool[bi][3];
                *(float4*)(out + b * 384 + layer_off + kk) = o;
            }
        }
    }
}

extern "C" void kernel_launch(void* const* d_in, const int* in_sizes, int n_in,
                              void* d_out, int out_size, void* d_ws, size_t ws_size,
                              hipStream_t stream) {
    const float* x  = (const float*)d_in[0];
    const float* k0 = (const float*)d_in[1];
    const float* k1 = (const float*)d_in[2];
    const float* k2 = (const float*)d_in[3];
    const float* bb0 = (const float*)d_in[4];
    const float* bb1 = (const float*)d_in[5];
    const float* bb2 = (const float*)d_in[6];
    float* out = (float*)d_out;
    char* ws = (char*)d_ws;

    // workspace layout; total = 173,015,040 B (== round-2 footprint, known good)
    ushort_t* x0bf = (ushort_t*)(ws);                 // 262144*64*2  = 33,554,432
    ushort_t* Kp0  = (ushort_t*)(ws + 33554432);      // 64*128*64*2  =  1,048,576
    ushort_t* Kp1  = (ushort_t*)(ws + 34603008);      // 128*128*64*2 =  2,097,152
    ushort_t* Kp2  = (ushort_t*)(ws + 36700160);      // 128*128*64*2 =  2,097,152
    ushort_t* fm0  = (ushort_t*)(ws + 38797312);      // 128*262144*2 = 67,108,864
    ushort_t* fm1  = (ushort_t*)(ws + 105906176);     // 128*262144*2 = 67,108,864
    ushort_t* x0T  = fm1;                             // 64*262144*2 aliases fm1 (dead after L0)

    cin_prep_x0bf<<<8192, 256, 0, stream>>>(x, x0bf);
    cin_prep_x0T<<<8192, 256, 0, stream>>>(x, x0T);
    cin_prep_k2<<<64, 256, 0, stream>>>(k0, Kp0, 64);
    cin_prep_k2<<<128, 256, 0, stream>>>(k1, Kp1, 128);
    cin_prep_k2<<<128, 256, 0, stream>>>(k2, Kp2, 128);

    cin_layer3<64, true><<<2048, 256, 0, stream>>>(x0bf, x0T, Kp0, bb0, fm0, out, 0);
    cin_layer3<128, true><<<2048, 256, 0, stream>>>(x0bf, fm0, Kp1, bb1, fm1, out, 128);
    cin_layer3<128, false><<<2048, 256, 0, stream>>>(x0bf, fm1, Kp2, bb2, (ushort_t*)nullptr, out, 256);
}

// Round 5
// 2546.992 us; speedup vs baseline: 1.3024x; 1.3024x over previous
//
#include <hip/hip_runtime.h>

typedef unsigned short ushort_t;
typedef unsigned int u32;
typedef __attribute__((ext_vector_type(8))) short bf16x8;
typedef __attribute__((ext_vector_type(4))) float f32x4;
typedef __attribute__((ext_vector_type(4))) u32 u32x4;

#define NTOT 262144  // B*D columns

__device__ __forceinline__ ushort_t f2b_rne(float f) {
    u32 u = __builtin_bit_cast(u32, f);
    u32 r = u + 0x7FFFu + ((u >> 16) & 1u);
    return (ushort_t)(r >> 16);
}
__device__ __forceinline__ u32 cvtpk(float lo, float hi) {
    u32 r;
    asm("v_cvt_pk_bf16_f32 %0, %1, %2" : "=v"(r) : "v"(lo), "v"(hi));
    return r;
}
__device__ __forceinline__ void gl_lds16(const ushort_t* g, ushort_t* l) {
    __builtin_amdgcn_global_load_lds(
        (const __attribute__((address_space(1))) u32*)g,
        (__attribute__((address_space(3))) u32*)l, 16, 0, 0);
}
__device__ __forceinline__ void gl_lds4(const ushort_t* g, ushort_t* l) {
    __builtin_amdgcn_global_load_lds(
        (const __attribute__((address_space(1))) u32*)g,
        (__attribute__((address_space(3))) u32*)l, 4, 0, 0);
}

// ---- prep: x (B,64,32) f32 -> x0bf bf16 [n=(b*32+d)][64 h] (RNE) ----
__global__ void cin_prep_x0bf(const float* __restrict__ x, ushort_t* __restrict__ x0bf) {
    __shared__ float xs[64 * 33];
    const int b = blockIdx.x, t = threadIdx.x;
    const float4* src = (const float4*)(x + (size_t)b * 2048);
#pragma unroll
    for (int i = 0; i < 2; ++i) {
        float4 f = src[t + 256 * i];
        int e = (t + 256 * i) * 4;
        int h = e >> 5, d = e & 31;
        xs[h * 33 + d]     = f.x;
        xs[h * 33 + d + 1] = f.y;
        xs[h * 33 + d + 2] = f.z;
        xs[h * 33 + d + 3] = f.w;
    }
    __syncthreads();
    const int d = t >> 3, j8 = t & 7;
    u32 w[4];
#pragma unroll
    for (int q = 0; q < 4; ++q) {
        int h0 = j8 * 8 + 2 * q;
        w[q] = (u32)f2b_rne(xs[h0 * 33 + d]) | ((u32)f2b_rne(xs[(h0 + 1) * 33 + d]) << 16);
    }
    uint4 o; o.x = w[0]; o.y = w[1]; o.z = w[2]; o.w = w[3];
    *(uint4*)(x0bf + ((size_t)b * 32 + d) * 64 + j8 * 8) = o;
}

// ---- prep: K (128,G,64) f32 -> Kp bf16 [g][k][64] with 16B-chunk XOR swizzle ----
__global__ void cin_prep_k2(const float* __restrict__ K, ushort_t* __restrict__ Kp, int G) {
    const int g = blockIdx.x, t = threadIdx.x;
    const int k = t >> 1, j0 = (t & 1) * 16;
    const float* s = K + ((size_t)k * G + g) * 64 + j0 * 2;
    u32* dst = (u32*)(Kp + (size_t)g * 8192 + k * 64);
    const int swc = k & 7;
#pragma unroll
    for (int c = 0; c < 4; ++c) {
        u32 w[4];
#pragma unroll
        for (int q = 0; q < 4; ++q) {
            int e = (c * 4 + q) * 2;
            w[q] = (u32)f2b_rne(s[e]) | ((u32)f2b_rne(s[e + 1]) << 16);
        }
        uint4 o; o.x = w[0]; o.y = w[1]; o.z = w[2]; o.w = w[3];
        *(uint4*)(dst + (((j0 >> 2) + c) ^ swc) * 4) = o;
    }
}

// ---- layer: fm[n,k] = relu( sum_g sum_h K[k,g,h]*xi[n,g]*x0[n,h] + bias[k] )
// K triple-buffered via gload_lds + counted vmcnt; xi gathered per-lane via gload_lds(4B)
// into 3x512B pair-buffers; x0 held packed-bf16 in 32 VGPRs, B-frag built in-register.
template <int G, bool STORE_FM>
__launch_bounds__(256, 3)
__global__ void cin_layer4(const ushort_t* __restrict__ x0bf,   // [NTOT][64]
                           const ushort_t* __restrict__ xi_src, // [NTOT][G] (row-major)
                           const ushort_t* __restrict__ Kp,     // [G][128][64] swizzled
                           const float* __restrict__ bias,      // [128]
                           ushort_t* __restrict__ fm_out,       // [NTOT][128]
                           float* __restrict__ out,             // [B][384]
                           int layer_off) {
    constexpr int P = G / 2;
    __shared__ ushort_t k_lds_flat[3 * 8192];  // 48 KB, swizzled rows [128][64]
    __shared__ ushort_t xi_flat[3 * 256];      // 3 x 512 B pair-tiles [128 rows][2 g]

    const int t = threadIdx.x;
    const int wg = blockIdx.x;
    const int lane = t & 63;
    const int wave = t >> 6;
    const int wm = wave >> 1, wn = wave & 1;
    const int col = lane & 15, g4 = lane >> 4;
    const int swz = (col & 7) << 3;
    const size_t n0 = (size_t)wg * 128;

    auto issueK = [&](int kg, int slot) {
        const ushort_t* src = Kp + (size_t)kg * 8192 + (size_t)t * 8;
        ushort_t* dst = k_lds_flat + slot * 8192 + t * 8;
#pragma unroll
        for (int i = 0; i < 4; ++i) gl_lds16(src + i * 2048, dst + i * 2048);
    };
    auto issueXi = [&](int pi, int slot) {
        const size_t r0 = n0 + lane;
        gl_lds4(xi_src + r0 * G + pi * 2, xi_flat + slot * 256 + lane * 2);
        gl_lds4(xi_src + (r0 + 64) * G + pi * 2, xi_flat + slot * 256 + 128 + lane * 2);
    };

    // ---- load x0 base packed (32 dwords) ----
    u32x4 pk4[8];
#pragma unroll
    for (int nf = 0; nf < 4; ++nf) {
        const size_t n_g = n0 + wn * 64 + nf * 16 + col;
#pragma unroll
        for (int ks2 = 0; ks2 < 2; ++ks2)
            pk4[nf * 2 + ks2] = *(const u32x4*)(x0bf + n_g * 64 + ks2 * 32 + g4 * 8);
    }
    // pin packed x0 in regs (forces loads drained before counted sequence starts)
#pragma unroll
    for (int i = 0; i < 8; ++i) {
#pragma unroll
        for (int q = 0; q < 4; ++q) asm volatile("" :: "v"(pk4[i][q]));
    }

    // ---- prologue issues: K0, xi(p0), K1, xi(p1)  (order defines vmcnt FIFO) ----
    issueK(0, 0);
    issueXi(0, 0);
    issueK(1, 1);
    issueXi((P > 1) ? 1 : 0, 1);

    f32x4 acc[4][4];
#pragma unroll
    for (int a = 0; a < 4; ++a)
#pragma unroll
        for (int b = 0; b < 4; ++b) acc[a][b] = (f32x4){0.f, 0.f, 0.f, 0.f};

    asm volatile("s_waitcnt vmcnt(6)" ::: "memory");  // retain K1 + xi(p1)
    __builtin_amdgcn_s_barrier();
    __builtin_amdgcn_sched_barrier(0);

    u32 xr_cur[4], xr_nxt[4];
#pragma unroll
    for (int nf = 0; nf < 4; ++nf)
        xr_cur[nf] = *(const u32*)(xi_flat + wn * 128 + (nf * 16 + col) * 2);

    auto COMPUTE = [&](int rslot, const float* xif) {
        const ushort_t* kbuf = k_lds_flat + rslot * 8192;
#pragma unroll
        for (int ks2 = 0; ks2 < 2; ++ks2) {
            bf16x8 bw[4], af[4];
#pragma unroll
            for (int nf = 0; nf < 4; ++nf) {
                u32x4 o;
#pragma unroll
                for (int q = 0; q < 4; ++q) {
                    u32 wv = pk4[nf * 2 + ks2][q];
                    float lo = __builtin_bit_cast(float, wv << 16);
                    float hi = __builtin_bit_cast(float, wv & 0xFFFF0000u);
                    o[q] = cvtpk(lo * xif[nf], hi * xif[nf]);
                }
                bw[nf] = __builtin_bit_cast(bf16x8, o);
            }
#pragma unroll
            for (int mf = 0; mf < 4; ++mf)
                af[mf] = *(const bf16x8*)(kbuf + (wm * 64 + mf * 16 + col) * 64 +
                                          ((ks2 * 32 + g4 * 8) ^ swz));
            __builtin_amdgcn_s_setprio(1);
#pragma unroll
            for (int mf = 0; mf < 4; ++mf)
#pragma unroll
                for (int nf = 0; nf < 4; ++nf)
                    acc[mf][nf] = __builtin_amdgcn_mfma_f32_16x16x32_bf16(
                        af[mf], bw[nf], acc[mf][nf], 0, 0, 0);
            __builtin_amdgcn_s_setprio(0);
        }
    };

    int m0 = 0, xs = 0;
#pragma unroll 1
    for (int p = 0; p < P; ++p) {
        const int g = 2 * p;
        {   // EVEN g: issue K(g+2), xi(p+2); compute slot m0; vmcnt(6)
            int kg = g + 2; if (kg > G - 1) kg = G - 1;
            int pi = p + 2; if (pi > P - 1) pi = P - 1;
            int wK = m0 + 2; if (wK >= 3) wK -= 3;
            int wX = xs + 2; if (wX >= 3) wX -= 3;
            issueK(kg, wK);
            issueXi(pi, wX);
            float xif[4];
#pragma unroll
            for (int nf = 0; nf < 4; ++nf)
                xif[nf] = __builtin_bit_cast(float, xr_cur[nf] << 16);
            COMPUTE(m0, xif);
            asm volatile("s_waitcnt vmcnt(6)" ::: "memory");
            __builtin_amdgcn_s_barrier();
            __builtin_amdgcn_sched_barrier(0);
        }
        {   // ODD g+1: issue K(g+3) into slot m0; compute slot m0+1; vmcnt(4)
            int kg = g + 3; if (kg > G - 1) kg = G - 1;
            issueK(kg, m0);
            float xif[4];
#pragma unroll
            for (int nf = 0; nf < 4; ++nf)
                xif[nf] = __builtin_bit_cast(float, xr_cur[nf] & 0xFFFF0000u);
            int r1 = m0 + 1; if (r1 >= 3) r1 -= 3;
            COMPUTE(r1, xif);
            int xn = xs + 1; if (xn >= 3) xn -= 3;
#pragma unroll
            for (int nf = 0; nf < 4; ++nf)
                xr_nxt[nf] = *(const u32*)(xi_flat + xn * 256 + wn * 128 + (nf * 16 + col) * 2);
            asm volatile("s_waitcnt vmcnt(4)" ::: "memory");
            __builtin_amdgcn_s_barrier();
            __builtin_amdgcn_sched_barrier(0);
#pragma unroll
            for (int nf = 0; nf < 4; ++nf) xr_cur[nf] = xr_nxt[nf];
            m0 += 2; if (m0 >= 3) m0 -= 3;
            xs += 1; if (xs >= 3) xs -= 3;
        }
    }

    // ---- epilogue: bias+relu, fm [n][128] coalesced uint2 store, pooled d-sum -> out ----
#pragma unroll
    for (int mf = 0; mf < 4; ++mf) {
        const int kk = wm * 64 + mf * 16 + g4 * 4;
        const float4 bs = *(const float4*)(bias + kk);
        float pool[2][4] = {{0.f, 0.f, 0.f, 0.f}, {0.f, 0.f, 0.f, 0.f}};
#pragma unroll
        for (int nf = 0; nf < 4; ++nf) {
            const size_t n_g = n0 + wn * 64 + nf * 16 + col;
            float v[4];
#pragma unroll
            for (int r = 0; r < 4; ++r) {
                float vv = acc[mf][nf][r] + ((r == 0) ? bs.x : (r == 1) ? bs.y : (r == 2) ? bs.z : bs.w);
                vv = fmaxf(vv, 0.f);
                v[r] = vv;
                pool[nf >> 1][r] += vv;
            }
            if (STORE_FM) {
                uint2 ww;
                ww.x = (u32)f2b_rne(v[0]) | ((u32)f2b_rne(v[1]) << 16);
                ww.y = (u32)f2b_rne(v[2]) | ((u32)f2b_rne(v[3]) << 16);
                *(uint2*)(fm_out + n_g * 128 + kk) = ww;
            }
        }
#pragma unroll
        for (int bi = 0; bi < 2; ++bi) {
#pragma unroll
            for (int r = 0; r < 4; ++r) {
                float s = pool[bi][r];
                s += __shfl_xor(s, 1, 16);
                s += __shfl_xor(s, 2, 16);
                s += __shfl_xor(s, 4, 16);
                s += __shfl_xor(s, 8, 16);
                pool[bi][r] = s;
            }
            if (col == 0) {
                const long b = (long)wg * 4 + wn * 2 + bi;
                float4 o;
                o.x = pool[bi][0]; o.y = pool[bi][1]; o.z = pool[bi][2]; o.w = pool[bi][3];
                *(float4*)(out + b * 384 + layer_off + kk) = o;
            }
        }
    }
}

extern "C" void kernel_launch(void* const* d_in, const int* in_sizes, int n_in,
                              void* d_out, int out_size, void* d_ws, size_t ws_size,
                              hipStream_t stream) {
    const float* x  = (const float*)d_in[0];
    const float* k0 = (const float*)d_in[1];
    const float* k1 = (const float*)d_in[2];
    const float* k2 = (const float*)d_in[3];
    const float* bb0 = (const float*)d_in[4];
    const float* bb1 = (const float*)d_in[5];
    const float* bb2 = (const float*)d_in[6];
    float* out = (float*)d_out;
    char* ws = (char*)d_ws;

    // workspace layout; total = 172,966,912 B
    ushort_t* x0bf = (ushort_t*)(ws);                 // 262144*64*2  = 33,554,432
    ushort_t* Kp0  = (ushort_t*)(ws + 33554432);      // 64*128*64*2  =  1,048,576
    ushort_t* Kp1  = (ushort_t*)(ws + 34603008);      // 128*128*64*2 =  2,097,152
    ushort_t* Kp2  = (ushort_t*)(ws + 36700160);      // 128*128*64*2 =  2,097,152
    ushort_t* fm0  = (ushort_t*)(ws + 38797312);      // 262144*128*2 = 67,108,864
    ushort_t* fm1  = (ushort_t*)(ws + 105906176);     // 262144*128*2 = 67,108,864

    cin_prep_x0bf<<<8192, 256, 0, stream>>>(x, x0bf);
    cin_prep_k2<<<64, 256, 0, stream>>>(k0, Kp0, 64);
    cin_prep_k2<<<128, 256, 0, stream>>>(k1, Kp1, 128);
    cin_prep_k2<<<128, 256, 0, stream>>>(k2, Kp2, 128);

    // layer 0: xi == x0 in [n][64] layout == x0bf itself
    cin_layer4<64, true><<<2048, 256, 0, stream>>>(x0bf, x0bf, Kp0, bb0, fm0, out, 0);
    cin_layer4<128, true><<<2048, 256, 0, stream>>>(x0bf, fm0, Kp1, bb1, fm1, out, 128);
    cin_layer4<128, false><<<2048, 256, 0, stream>>>(x0bf, fm1, Kp2, bb2, (ushort_t*)nullptr, out, 256);
}

// Round 6
// 1268.129 us; speedup vs baseline: 2.6159x; 2.0085x over previous
//
#include <hip/hip_runtime.h>

typedef unsigned short ushort_t;
typedef unsigned int u32;
typedef __attribute__((ext_vector_type(8))) short bf16x8;
typedef __attribute__((ext_vector_type(4))) float f32x4;
typedef __attribute__((ext_vector_type(2))) float f32x2;
typedef __attribute__((ext_vector_type(4))) u32 u32x4;

#define NTOT 262144  // B*D columns

__device__ __forceinline__ ushort_t f2b_rne(float f) {
    u32 u = __builtin_bit_cast(u32, f);
    u32 r = u + 0x7FFFu + ((u >> 16) & 1u);
    return (ushort_t)(r >> 16);
}
// (even,odd) f32 pair * (s,s) -> packed bf16 dword (RNE): v_pk_mul_f32 + v_cvt_pk_bf16_f32
__device__ __forceinline__ u32 scale_pack(f32x2 xp, f32x2 s) {
    f32x2 d;
    asm("v_pk_mul_f32 %0, %1, %2" : "=v"(d) : "v"(xp), "v"(s));
    u32 r;
    asm("v_cvt_pk_bf16_f32 %0, %1, %2" : "=v"(r) : "v"(d[0]), "v"(d[1]));
    return r;
}
__device__ __forceinline__ void gl_lds16(const ushort_t* g, ushort_t* l) {
    __builtin_amdgcn_global_load_lds(
        (const __attribute__((address_space(1))) u32*)g,
        (__attribute__((address_space(3))) u32*)l, 16, 0, 0);
}

// ---- prep: x (B,64,32) f32 -> x0bf bf16 [n=(b*32+d)][64 h] (RNE) ----
__global__ void cin_prep_x0bf(const float* __restrict__ x, ushort_t* __restrict__ x0bf) {
    __shared__ float xs[64 * 33];
    const int b = blockIdx.x, t = threadIdx.x;
    const float4* src = (const float4*)(x + (size_t)b * 2048);
#pragma unroll
    for (int i = 0; i < 2; ++i) {
        float4 f = src[t + 256 * i];
        int e = (t + 256 * i) * 4;
        int h = e >> 5, d = e & 31;
        xs[h * 33 + d]     = f.x;
        xs[h * 33 + d + 1] = f.y;
        xs[h * 33 + d + 2] = f.z;
        xs[h * 33 + d + 3] = f.w;
    }
    __syncthreads();
    const int d = t >> 3, j8 = t & 7;
    u32 w[4];
#pragma unroll
    for (int q = 0; q < 4; ++q) {
        int h0 = j8 * 8 + 2 * q;
        w[q] = (u32)f2b_rne(xs[h0 * 33 + d]) | ((u32)f2b_rne(xs[(h0 + 1) * 33 + d]) << 16);
    }
    uint4 o; o.x = w[0]; o.y = w[1]; o.z = w[2]; o.w = w[3];
    *(uint4*)(x0bf + ((size_t)b * 32 + d) * 64 + j8 * 8) = o;
}

// ---- prep: K (128,G,64) f32 -> Kp bf16 [g][k][64] with 16B-chunk XOR swizzle ----
__global__ void cin_prep_k2(const float* __restrict__ K, ushort_t* __restrict__ Kp, int G) {
    const int g = blockIdx.x, t = threadIdx.x;
    const int k = t >> 1, j0 = (t & 1) * 16;
    const float* s = K + ((size_t)k * G + g) * 64 + j0 * 2;
    u32* dst = (u32*)(Kp + (size_t)g * 8192 + k * 64);
    const int swc = k & 7;
#pragma unroll
    for (int c = 0; c < 4; ++c) {
        u32 w[4];
#pragma unroll
        for (int q = 0; q < 4; ++q) {
            int e = (c * 4 + q) * 2;
            w[q] = (u32)f2b_rne(s[e]) | ((u32)f2b_rne(s[e + 1]) << 16);
        }
        uint4 o; o.x = w[0]; o.y = w[1]; o.z = w[2]; o.w = w[3];
        *(uint4*)(dst + (((j0 >> 2) + c) ^ swc) * 4) = o;
    }
}

// ---- layer: fm[n,k] = relu( sum_g sum_h K[k,g,h]*xi[n,g]*x0[n,h] + bias[k] )
// K triple-buffered LDS (gload_lds w16, counted vmcnt(4), 1 barrier/g);
// xi in registers (per-thread dwordx4 per 8-g chunk, A/B double-buffered, static idx);
// x0 unpacked f32 pairs in regs; B-frag 2 VALU ops/dword.
template <int G, bool STORE_FM>
__launch_bounds__(256, 2)
__global__ void cin_layer5(const ushort_t* __restrict__ x0bf,   // [NTOT][64]
                           const ushort_t* __restrict__ xi_src, // [NTOT][G] rows
                           const ushort_t* __restrict__ Kp,     // [G][128][64] swizzled
                           const float* __restrict__ bias,      // [128]
                           ushort_t* __restrict__ fm_out,       // [NTOT][128]
                           float* __restrict__ out,             // [B][384]
                           int layer_off) {
    constexpr int NC = G / 8;  // 8-g xi chunks
    __shared__ ushort_t k_lds[3 * 8192];  // 48 KB

    const int t = threadIdx.x;
    const int wg = blockIdx.x;
    const int lane = t & 63;
    const int wave = t >> 6;
    const int wm = wave >> 1, wn = wave & 1;
    const int col = lane & 15, g4 = lane >> 4;
    const int swz = (col & 7) << 3;
    const size_t n0 = (size_t)wg * 128;

    auto issueK = [&](int kg, int slot) {
        const ushort_t* src = Kp + (size_t)kg * 8192 + (size_t)t * 8;
        ushort_t* dst = k_lds + slot * 8192 + t * 8;
#pragma unroll
        for (int i = 0; i < 4; ++i) gl_lds16(src + i * 2048, dst + i * 2048);
    };

    // per-thread xi row pointers (4 rows, one per nf)
    const ushort_t* xrow[4];
#pragma unroll
    for (int nf = 0; nf < 4; ++nf)
        xrow[nf] = xi_src + (n0 + wn * 64 + nf * 16 + col) * G;

    // ---- x0 base -> unpacked (even,odd) f32 pairs: 64 VGPRs ----
    f32x2 xb[4][8];
#pragma unroll
    for (int nf = 0; nf < 4; ++nf) {
        const size_t n_g = n0 + wn * 64 + nf * 16 + col;
#pragma unroll
        for (int ks2 = 0; ks2 < 2; ++ks2) {
            u32x4 v = *(const u32x4*)(x0bf + n_g * 64 + ks2 * 32 + g4 * 8);
#pragma unroll
            for (int q = 0; q < 4; ++q) {
                f32x2 p;
                p[0] = __builtin_bit_cast(float, v[q] << 16);
                p[1] = __builtin_bit_cast(float, v[q] & 0xFFFF0000u);
                xb[nf][ks2 * 4 + q] = p;
            }
        }
    }

    // xi chunk 0 into A buffer
    u32x4 xcA[4], xcB[4];
#pragma unroll
    for (int nf = 0; nf < 4; ++nf) xcA[nf] = *(const u32x4*)(xrow[nf]);

    issueK(0, 0);
    issueK(1, 1);

    f32x4 acc[4][4];
#pragma unroll
    for (int a = 0; a < 4; ++a)
#pragma unroll
        for (int b = 0; b < 4; ++b) acc[a][b] = (f32x4){0.f, 0.f, 0.f, 0.f};

    asm volatile("s_waitcnt vmcnt(4)" ::: "memory");  // K0 + all reg-loads landed; K1 in flight
    __builtin_amdgcn_s_barrier();
    __builtin_amdgcn_sched_barrier(0);

    int sr = 0, sw = 2;  // read slot, write slot (mod 3)

    auto CHUNK = [&](int c, u32x4 (&cur)[4], u32x4 (&nxt)[4]) {
#pragma unroll
        for (int gi = 0; gi < 8; ++gi) {
            const int g = c * 8 + gi;
            if (gi == 0) {  // prefetch next xi chunk into nxt (used 8 iters later)
                int cn = c + 1; if (cn > NC - 1) cn = NC - 1;
#pragma unroll
                for (int nf = 0; nf < 4; ++nf)
                    nxt[nf] = *(const u32x4*)(xrow[nf] + cn * 8);
            }
            int kg = g + 2; if (kg > G - 1) kg = G - 1;
            issueK(kg, sw);
            // B fragments in-register (2 ops/dword)
            bf16x8 bw[4][2];
#pragma unroll
            for (int nf = 0; nf < 4; ++nf) {
                u32 xw = cur[nf][gi >> 1];
                u32 xs32 = (gi & 1) ? (xw & 0xFFFF0000u) : (xw << 16);
                float xf = __builtin_bit_cast(float, xs32);
                f32x2 s; s[0] = xf; s[1] = xf;
#pragma unroll
                for (int ks2 = 0; ks2 < 2; ++ks2) {
                    u32x4 o;
#pragma unroll
                    for (int q = 0; q < 4; ++q)
                        o[q] = scale_pack(xb[nf][ks2 * 4 + q], s);
                    bw[nf][ks2] = __builtin_bit_cast(bf16x8, o);
                }
            }
            // A fragments + 32 MFMA
            const ushort_t* kbuf = k_lds + sr * 8192;
#pragma unroll
            for (int ks2 = 0; ks2 < 2; ++ks2) {
                bf16x8 af[4];
#pragma unroll
                for (int mf = 0; mf < 4; ++mf)
                    af[mf] = *(const bf16x8*)(kbuf + (wm * 64 + mf * 16 + col) * 64 +
                                              ((ks2 * 32 + g4 * 8) ^ swz));
                __builtin_amdgcn_s_setprio(1);
#pragma unroll
                for (int mf = 0; mf < 4; ++mf)
#pragma unroll
                    for (int nf = 0; nf < 4; ++nf)
                        acc[mf][nf] = __builtin_amdgcn_mfma_f32_16x16x32_bf16(
                            af[mf], bw[nf][ks2], acc[mf][nf], 0, 0, 0);
                __builtin_amdgcn_s_setprio(0);
            }
            asm volatile("s_waitcnt vmcnt(4)" ::: "memory");  // K(g+1) landed; K(g+2) in flight
            __builtin_amdgcn_s_barrier();
            __builtin_amdgcn_sched_barrier(0);
            sr = (sr == 2) ? 0 : sr + 1;
            sw = (sw == 2) ? 0 : sw + 1;
        }
    };

#pragma unroll 1
    for (int c = 0; c < NC; c += 2) {
        CHUNK(c, xcA, xcB);
        CHUNK(c + 1, xcB, xcA);
    }

    // ---- epilogue: bias+relu, fm [n][128] coalesced uint2 store, pooled d-sum -> out ----
#pragma unroll
    for (int mf = 0; mf < 4; ++mf) {
        const int kk = wm * 64 + mf * 16 + g4 * 4;
        const float4 bs = *(const float4*)(bias + kk);
        float pool[2][4] = {{0.f, 0.f, 0.f, 0.f}, {0.f, 0.f, 0.f, 0.f}};
#pragma unroll
        for (int nf = 0; nf < 4; ++nf) {
            const size_t n_g = n0 + wn * 64 + nf * 16 + col;
            float v[4];
#pragma unroll
            for (int r = 0; r < 4; ++r) {
                float vv = acc[mf][nf][r] + ((r == 0) ? bs.x : (r == 1) ? bs.y : (r == 2) ? bs.z : bs.w);
                vv = fmaxf(vv, 0.f);
                v[r] = vv;
                pool[nf >> 1][r] += vv;
            }
            if (STORE_FM) {
                uint2 ww;
                ww.x = (u32)f2b_rne(v[0]) | ((u32)f2b_rne(v[1]) << 16);
                ww.y = (u32)f2b_rne(v[2]) | ((u32)f2b_rne(v[3]) << 16);
                *(uint2*)(fm_out + n_g * 128 + kk) = ww;
            }
        }
#pragma unroll
        for (int bi = 0; bi < 2; ++bi) {
#pragma unroll
            for (int r = 0; r < 4; ++r) {
                float s = pool[bi][r];
                s += __shfl_xor(s, 1, 16);
                s += __shfl_xor(s, 2, 16);
                s += __shfl_xor(s, 4, 16);
                s += __shfl_xor(s, 8, 16);
                pool[bi][r] = s;
            }
            if (col == 0) {
                const long b = (long)wg * 4 + wn * 2 + bi;
                float4 o;
                o.x = pool[bi][0]; o.y = pool[bi][1]; o.z = pool[bi][2]; o.w = pool[bi][3];
                *(float4*)(out + b * 384 + layer_off + kk) = o;
            }
        }
    }
}

extern "C" void kernel_launch(void* const* d_in, const int* in_sizes, int n_in,
                              void* d_out, int out_size, void* d_ws, size_t ws_size,
                              hipStream_t stream) {
    const float* x  = (const float*)d_in[0];
    const float* k0 = (const float*)d_in[1];
    const float* k1 = (const float*)d_in[2];
    const float* k2 = (const float*)d_in[3];
    const float* bb0 = (const float*)d_in[4];
    const float* bb1 = (const float*)d_in[5];
    const float* bb2 = (const float*)d_in[6];
    float* out = (float*)d_out;
    char* ws = (char*)d_ws;

    // workspace layout; total = 172,966,912 B
    ushort_t* x0bf = (ushort_t*)(ws);                 // 262144*64*2  = 33,554,432
    ushort_t* Kp0  = (ushort_t*)(ws + 33554432);      // 64*128*64*2  =  1,048,576
    ushort_t* Kp1  = (ushort_t*)(ws + 34603008);      // 128*128*64*2 =  2,097,152
    ushort_t* Kp2  = (ushort_t*)(ws + 36700160);      // 128*128*64*2 =  2,097,152
    ushort_t* fm0  = (ushort_t*)(ws + 38797312);      // 262144*128*2 = 67,108,864
    ushort_t* fm1  = (ushort_t*)(ws + 105906176);     // 262144*128*2 = 67,108,864

    cin_prep_x0bf<<<8192, 256, 0, stream>>>(x, x0bf);
    cin_prep_k2<<<64, 256, 0, stream>>>(k0, Kp0, 64);
    cin_prep_k2<<<128, 256, 0, stream>>>(k1, Kp1, 128);
    cin_prep_k2<<<128, 256, 0, stream>>>(k2, Kp2, 128);

    // layer 0: xi == x0 in [n][64] layout == x0bf itself
    cin_layer5<64, true><<<2048, 256, 0, stream>>>(x0bf, x0bf, Kp0, bb0, fm0, out, 0);
    cin_layer5<128, true><<<2048, 256, 0, stream>>>(x0bf, fm0, Kp1, bb1, fm1, out, 128);
    cin_layer5<128, false><<<2048, 256, 0, stream>>>(x0bf, fm1, Kp2, bb2, (ushort_t*)nullptr, out, 256);
}